// Round 14
// baseline (107.413 us; speedup 1.0000x reference)
//
#include <hip/hip_runtime.h>
#include <hip/hip_bf16.h>
#include <math.h>

typedef __bf16 bf16x8 __attribute__((ext_vector_type(8)));
typedef __bf16 bf16x2 __attribute__((ext_vector_type(2)));
typedef float  floatx16 __attribute__((ext_vector_type(16)));
typedef float  f32x2   __attribute__((ext_vector_type(2)));
typedef unsigned u32x4 __attribute__((ext_vector_type(4)));

// Workspace layout (bytes):
//   Kq    bf16 [2][8192][16]        offset 0        (512 KB)  scaled by sqrt(log2 e)
//   Vswz  bf16 [2][8192][32]        offset 524288   (1 MB)    P-natural-order B-frag swizzle
//   Opart bf16 [2*8192][8][32]      offset 1572864  (8.4 MB)  normalized ratios r_s = O_s/l_s
//   Lpart f32  [2*8192][8]          after Opart     (512 KB)
#define KQ_ELEMS (2 * 8192 * 16)
#define OPART_OFF 1572864
#define SQRT_LOG2E 1.2011224087864498f
#define LSPLIT 3

// ---------------- Kernel A: projections ----------------
// v8 proj (R13): o-range split across 2x blocks -> 1024 blocks x 256 thr.
// Vswz layout (v7, verified): P-natural slot order: f=jl>>4, jj=jl&15,
// h=(jj>>2)&1, idx=(jj&3)|(((jj>>3)&1)<<2), flat = jt*1024+f*512+h*256+c*8+idx.
__global__ __launch_bounds__(256) void proj_kernel(
    const float* __restrict__ in, const float* __restrict__ W1,
    const float* __restrict__ b1, const float* __restrict__ W2,
    const float* __restrict__ b2,
    __hip_bfloat16* __restrict__ Kq, __hip_bfloat16* __restrict__ Vswz)
{
    __shared__ float Xs[32][32];
    __shared__ float W1s[8 * 32];
    __shared__ float W2s[16 * 32];
    const int t = threadIdx.x;
    const int bid = blockIdx.x;        // 0..1023
    const int b = bid >> 9;
    const int hw = (bid >> 1) & 255;
    const int half = bid & 1;

    {
        int l = t >> 3, cs = (t & 7) * 4;
        float4 v = *(const float4*)(in + (((size_t)b * 32 + l) * 256 + hw) * 32 + cs);
        *(float4*)&Xs[l][cs] = v;
    }
    if (t < 64)  *(float4*)&W1s[t * 4] = *(const float4*)(W1 + half * 8 * 32 + t * 4);
    if (t < 128) *(float4*)&W2s[t * 4] = *(const float4*)(W2 + half * 16 * 32 + t * 4);
    __syncthreads();

    const int c = t & 31;
    const int g = t >> 5;              // 0..7

    {
        int o = half * 8 + g;          // 0..15
        float a0 = b1[o], a1 = 0.f;
#pragma unroll
        for (int l = 0; l < 16; ++l) {
            a0 += W1s[g * 32 + l] * Xs[l][c];
            a1 += W1s[g * 32 + 16 + l] * Xs[16 + l][c];
        }
        float acc = a0 + a1;
        int k = c >> 1;
        int i = (c & 1) * 4096 + o * 256 + hw;
        Kq[((size_t)b * 8192 + i) * 16 + k] = __float2bfloat16(acc * SQRT_LOG2E);
    }
#pragma unroll
    for (int oo = 0; oo < 2; ++oo) {
        int ol = g * 2 + oo;           // 0..15 (local)
        int o = half * 16 + ol;        // 0..31 (global)
        float a0 = b2[o], a1 = 0.f;
#pragma unroll
        for (int l = 0; l < 16; ++l) {
            a0 += W2s[ol * 32 + l] * Xs[l][c];
            a1 += W2s[ol * 32 + 16 + l] * Xs[16 + l][c];
        }
        float acc = a0 + a1;
        // position j = o*256 + hw, channel c; P-natural-order swizzle (v7):
        int jt = o * 8 + (hw >> 5);
        int f  = (hw >> 4) & 1;
        int hh = (hw >> 2) & 1;
        int idx = (hw & 3) | (((hw >> 3) & 1) << 2);
        Vswz[(size_t)b * 262144 + jt * 1024 + f * 512 + hh * 256 + c * 8 + idx] =
            __float2bfloat16(acc);
    }
}

// Fast 2^x on the VALU (7 full-rate ops), replacing v_exp_f32.
// Theory (v14): the ONLY model consistent with all 12 rounds is a trans pipe at
// ~1/16 rate: 2048 wave-exp2/SIMD x 32cyc = 27.3us == the 29.5us plateau, and a
// saturated trans pipe is invariant to occupancy/ILP/prefetch/VALU-shift — every
// null explained. Quadratic minimax on [0,1): rel err <= 0.03% (bf16-P already
// carries 0.4%). Scores |s| <~ 30 -> exponent construction safe.
__device__ __forceinline__ float fast_exp2(float s) {
    float n = floorf(s);
    float f = s - n;
    float p = fmaf(f, fmaf(f, 0.34203151f, 0.65780077f), 1.00010959f);
    int e = ((int)n + 127) << 23;
    return p * __int_as_float(e);
}

// ---------------- Kernel B: flash attention, LDS-free, bf16 normalized partials ----------------
// v14 = R6/v7 structure (best config, 95.3 twice) with exp2 moved OFF the trans
// pipe (fast_exp2 above) + l-adds packed as float2 (v_pk_add_f32). Everything
// else byte-identical: P-natural V-swizzle (zero cross-lane), single oa, native
// x16 MFMAs, depth-1 prefetch, (256,4), streaming stores (NOT atomics).
__global__ __launch_bounds__(256, 4) void flash_kernel(
    const __hip_bfloat16* __restrict__ Kq, const __hip_bfloat16* __restrict__ Vswz,
    __hip_bfloat16* __restrict__ Opart, float* __restrict__ Lpart)
{
    const int t = threadIdx.x;
    const int lane = t & 63;
    const int wv = t >> 6;            // 0..3
    const int m = lane & 31;
    const int h = lane >> 5;          // 0/1

    const int bid = blockIdx.x;
    const int s = bid & ((1 << LSPLIT) - 1);
    const int itile = (bid >> LSPLIT) & 63;
    const int b = bid >> (LSPLIT + 6);
    const int i0 = itile * 128 + wv * 32;
    const int niter = (8192 >> LSPLIT) >> 5;   // 32 tiles of 32 j
    const int jt0 = s * niter;

    const __hip_bfloat16* Kb = Kq + (size_t)b * 8192 * 16;
    const __hip_bfloat16* Vb = Vswz + (size_t)b * 262144 + h * 256 + m * 8;

    // Q B-frag (regs): B[k=8h+idx][n=m] = Kq[i0+m][8h+idx]
    const bf16x8 bq = *(const bf16x8*)(Kb + (size_t)(i0 + m) * 16 + h * 8);

    floatx16 oa = {};
    f32x2 l01 = {0.f, 0.f}, l23 = {0.f, 0.f};

    // ---- software pipeline: preload tile jt0 ----
    bf16x8 ak = *(const bf16x8*)(Kb + (size_t)(jt0 * 32 + m) * 16 + h * 8);
    bf16x8 vb0 = *(const bf16x8*)(Vb + (size_t)jt0 * 1024 + 0);
    bf16x8 vb1 = *(const bf16x8*)(Vb + (size_t)jt0 * 1024 + 512);

#pragma unroll 2
    for (int it = 0; it < niter; ++it) {
        const bf16x8 cak = ak;
        const bf16x8 cv0 = vb0, cv1 = vb1;
        if (it + 1 < niter) {
            const int jn = jt0 + it + 1;
            ak  = *(const bf16x8*)(Kb + (size_t)(jn * 32 + m) * 16 + h * 8);
            vb0 = *(const bf16x8*)(Vb + (size_t)jn * 1024 + 0);
            vb1 = *(const bf16x8*)(Vb + (size_t)jn * 1024 + 512);
        }

        // S^T(32j x 32i) = K(A) x Q(B), K=16 exact
        floatx16 sc = __builtin_amdgcn_mfma_f32_32x32x16_bf16(cak, bq, (floatx16){}, 0, 0, 0);

        // P = 2^S via VALU fast_exp2 ; sc reg 4g+idx holds j_loc = 8g+4h+idx, i = m.
        // cvt_pk pairs ARE the A-frag dwords under the v7 V-swizzle.
#pragma unroll
        for (int half = 0; half < 2; ++half) {
            u32x4 pau;
#pragma unroll
            for (int gg = 0; gg < 2; ++gg) {
                const int g = half * 2 + gg;
                float e0 = fast_exp2(sc[4 * g + 0]);
                float e1 = fast_exp2(sc[4 * g + 1]);
                float e2 = fast_exp2(sc[4 * g + 2]);
                float e3 = fast_exp2(sc[4 * g + 3]);
                f32x2 p01 = {e0, e1}, p23 = {e2, e3};
                l01 += p01; l23 += p23;               // v_pk_add_f32
#if defined(__has_builtin) && __has_builtin(__builtin_amdgcn_cvt_pk_bf16_f32)
                bf16x2 pk0 = __builtin_amdgcn_cvt_pk_bf16_f32(e0, e1);
                bf16x2 pk1 = __builtin_amdgcn_cvt_pk_bf16_f32(e2, e3);
#else
                bf16x2 pk0 = {(__bf16)e0, (__bf16)e1};
                bf16x2 pk1 = {(__bf16)e2, (__bf16)e3};
#endif
                pau[gg * 2 + 0] = __builtin_bit_cast(unsigned, pk0);
                pau[gg * 2 + 1] = __builtin_bit_cast(unsigned, pk1);
            }
            bf16x8 pa = __builtin_bit_cast(bf16x8, pau);
            oa = __builtin_amdgcn_mfma_f32_32x32x16_bf16(pa, half ? cv1 : cv0, oa, 0, 0, 0);
        }
    }

    // full split-partial row-sum l_s for row i0+m (this lane's column)
    float l = (l01[0] + l01[1]) + (l23[0] + l23[1]);
    l += __shfl_xor(l, 32);
    const float rinv = __builtin_amdgcn_rcpf(l);

    // store normalized ratios r_s = O_s / l_s as bf16 (unit-scale, well-conditioned).
    // reg r -> row i_loc=(r&3)+8*(r>>2)+4h, col c=m ; l for row iloc lives in lane iloc
#pragma unroll
    for (int r = 0; r < 16; ++r) {
        int iloc = (r & 3) + 8 * (r >> 2) + 4 * h;
        float lr = __shfl(rinv, iloc);
        size_t row = (size_t)b * 8192 + i0 + iloc;
        Opart[((row << LSPLIT) | s) * 32 + m] = __float2bfloat16(oa[r] * lr);
    }
    if (h == 0)
        Lpart[(((size_t)b * 8192 + i0 + m) << LSPLIT) | s] = l;
}

// ---------------- Kernel C: weighted combine + epilogue ----------------
// out = (sum_s l_s * r_s) / (sum_s l_s) * gamma + in   (8 splits, LSPLIT=3)
// v5 combine (R13): 4 channels/thread, ushort4 Opart loads + float4 in/out.
__global__ __launch_bounds__(256) void combine_kernel(
    const unsigned short* __restrict__ Opart, const float* __restrict__ Lpart,
    const float* __restrict__ in, const float* __restrict__ gamma,
    float* __restrict__ out)
{
    const int gid = blockIdx.x * 256 + threadIdx.x;   // 0..131071
    const int row = gid >> 3;                          // 0..16383
    const int c4 = (gid & 7) * 4;
    const unsigned short* op = Opart + ((size_t)row << LSPLIT) * 32 + c4;
    const float* lp = Lpart + ((size_t)row << LSPLIT);
    float4 lv0 = *(const float4*)(lp);
    float4 lv1 = *(const float4*)(lp + 4);
    float ls8[8] = {lv0.x, lv0.y, lv0.z, lv0.w, lv1.x, lv1.y, lv1.z, lv1.w};
    float a0 = 0.f, a1 = 0.f, a2 = 0.f, a3 = 0.f;
    float lsum = 0.f;
#pragma unroll
    for (int s = 0; s < (1 << LSPLIT); ++s) {
        ushort4 u = *(const ushort4*)(op + s * 32);
        float ls = ls8[s];
        a0 += ls * __uint_as_float((unsigned)u.x << 16);
        a1 += ls * __uint_as_float((unsigned)u.y << 16);
        a2 += ls * __uint_as_float((unsigned)u.z << 16);
        a3 += ls * __uint_as_float((unsigned)u.w << 16);
        lsum += ls;
    }
    const size_t base = (size_t)row * 32 + c4;
    float4 x = *(const float4*)(in + base);
    const float gl = gamma[0] / lsum;
    float4 r;
    r.x = a0 * gl + x.x;
    r.y = a1 * gl + x.y;
    r.z = a2 * gl + x.z;
    r.w = a3 * gl + x.w;
    *(float4*)(out + base) = r;
}

extern "C" void kernel_launch(void* const* d_in, const int* in_sizes, int n_in,
                              void* d_out, int out_size, void* d_ws, size_t ws_size,
                              hipStream_t stream) {
    const float* in = (const float*)d_in[0];
    const float* W1 = (const float*)d_in[1];
    const float* b1 = (const float*)d_in[2];
    const float* W2 = (const float*)d_in[3];
    const float* b2 = (const float*)d_in[4];
    const float* gamma = (const float*)d_in[5];
    float* out = (float*)d_out;

    __hip_bfloat16* Kq = (__hip_bfloat16*)d_ws;
    __hip_bfloat16* Vswz = Kq + KQ_ELEMS;
    __hip_bfloat16* Opart = (__hip_bfloat16*)((char*)d_ws + OPART_OFF);
    float* Lpart = (float*)(Opart + ((size_t)16384 << LSPLIT) * 32);

    proj_kernel<<<1024, 256, 0, stream>>>(in, W1, b1, W2, b2, Kq, Vswz);
    flash_kernel<<<2 * 64 * (1 << LSPLIT), 256, 0, stream>>>(Kq, Vswz, Opart, Lpart);
    combine_kernel<<<512, 256, 0, stream>>>((const unsigned short*)Opart, Lpart, in, gamma, out);
}

// Round 15
// 95.126 us; speedup vs baseline: 1.1292x; 1.1292x over previous
//
#include <hip/hip_runtime.h>
#include <hip/hip_bf16.h>
#include <math.h>

typedef __bf16 bf16x8 __attribute__((ext_vector_type(8)));
typedef __bf16 bf16x2 __attribute__((ext_vector_type(2)));
typedef float  floatx16 __attribute__((ext_vector_type(16)));
typedef unsigned u32x4 __attribute__((ext_vector_type(4)));

// Workspace layout (bytes):
//   Kq    bf16 [2][8192][16]        offset 0        (512 KB)  scaled by sqrt(log2 e)
//   Vswz  bf16 [2][8192][32]        offset 524288   (1 MB)    P-natural-order B-frag swizzle
//   Opart bf16 [2*8192][8][32]      offset 1572864  (8.4 MB)  normalized ratios r_s = O_s/l_s
//   Lpart f32  [2*8192][8]          after Opart     (512 KB)
#define KQ_ELEMS (2 * 8192 * 16)
#define OPART_OFF 1572864
#define SQRT_LOG2E 1.2011224087864498f
#define LSPLIT 3

// ---------------- Kernel A: projections ----------------
// v8 proj (R13): o-range split across 2x blocks -> 1024 blocks x 256 thr.
// Vswz layout (v7, verified): P-natural slot order: f=jl>>4, jj=jl&15,
// h=(jj>>2)&1, idx=(jj&3)|(((jj>>3)&1)<<2), flat = jt*1024+f*512+h*256+c*8+idx.
__global__ __launch_bounds__(256) void proj_kernel(
    const float* __restrict__ in, const float* __restrict__ W1,
    const float* __restrict__ b1, const float* __restrict__ W2,
    const float* __restrict__ b2,
    __hip_bfloat16* __restrict__ Kq, __hip_bfloat16* __restrict__ Vswz)
{
    __shared__ float Xs[32][32];
    __shared__ float W1s[8 * 32];
    __shared__ float W2s[16 * 32];
    const int t = threadIdx.x;
    const int bid = blockIdx.x;        // 0..1023
    const int b = bid >> 9;
    const int hw = (bid >> 1) & 255;
    const int half = bid & 1;

    {
        int l = t >> 3, cs = (t & 7) * 4;
        float4 v = *(const float4*)(in + (((size_t)b * 32 + l) * 256 + hw) * 32 + cs);
        *(float4*)&Xs[l][cs] = v;
    }
    if (t < 64)  *(float4*)&W1s[t * 4] = *(const float4*)(W1 + half * 8 * 32 + t * 4);
    if (t < 128) *(float4*)&W2s[t * 4] = *(const float4*)(W2 + half * 16 * 32 + t * 4);
    __syncthreads();

    const int c = t & 31;
    const int g = t >> 5;              // 0..7

    {
        int o = half * 8 + g;          // 0..15
        float a0 = b1[o], a1 = 0.f;
#pragma unroll
        for (int l = 0; l < 16; ++l) {
            a0 += W1s[g * 32 + l] * Xs[l][c];
            a1 += W1s[g * 32 + 16 + l] * Xs[16 + l][c];
        }
        float acc = a0 + a1;
        int k = c >> 1;
        int i = (c & 1) * 4096 + o * 256 + hw;
        Kq[((size_t)b * 8192 + i) * 16 + k] = __float2bfloat16(acc * SQRT_LOG2E);
    }
#pragma unroll
    for (int oo = 0; oo < 2; ++oo) {
        int ol = g * 2 + oo;           // 0..15 (local)
        int o = half * 16 + ol;        // 0..31 (global)
        float a0 = b2[o], a1 = 0.f;
#pragma unroll
        for (int l = 0; l < 16; ++l) {
            a0 += W2s[ol * 32 + l] * Xs[l][c];
            a1 += W2s[ol * 32 + 16 + l] * Xs[16 + l][c];
        }
        float acc = a0 + a1;
        // position j = o*256 + hw, channel c; P-natural-order swizzle (v7):
        int jt = o * 8 + (hw >> 5);
        int f  = (hw >> 4) & 1;
        int hh = (hw >> 2) & 1;
        int idx = (hw & 3) | (((hw >> 3) & 1) << 2);
        Vswz[(size_t)b * 262144 + jt * 1024 + f * 512 + hh * 256 + c * 8 + idx] =
            __float2bfloat16(acc);
    }
}

// ---------------- Kernel B: flash attention, LDS-free, bf16 normalized partials ----------------
// FROZEN at the session-best config (R6/v7; 95.27-95.33us total, three times
// reproduced). Plateau evidence (R7-R14): occupancy 2/4/5/6 waves, i-ILP, j-ILP,
// prefetch depth 0/1/2, MFMA-l-sum, setprio, VALU-exp2 — all null or negative;
// flash pinned 28.5-30.5us. R14 calibrated the mechanism: added VALU ops land
// ~1:1 on the serial chain (+96 ops -> +216 cyc/iter), i.e. the kernel is bound
// by its intrinsic per-iteration instruction stream (16 exp2 + 8 cvt + 16 adds +
// 3 MFMAs + 3 loads for 134M-exp2 softmax). Only WORK REMOVAL ever moved it
// (reg economy 41->33, shuffle removal 33->29.5); nothing removable remains at
// HIP source level. DO NOT RE-TUNE SCHEDULING HERE.
__global__ __launch_bounds__(256, 4) void flash_kernel(
    const __hip_bfloat16* __restrict__ Kq, const __hip_bfloat16* __restrict__ Vswz,
    __hip_bfloat16* __restrict__ Opart, float* __restrict__ Lpart)
{
    const int t = threadIdx.x;
    const int lane = t & 63;
    const int wv = t >> 6;            // 0..3
    const int m = lane & 31;
    const int h = lane >> 5;          // 0/1

    const int bid = blockIdx.x;
    const int s = bid & ((1 << LSPLIT) - 1);
    const int itile = (bid >> LSPLIT) & 63;
    const int b = bid >> (LSPLIT + 6);
    const int i0 = itile * 128 + wv * 32;
    const int niter = (8192 >> LSPLIT) >> 5;   // 32 tiles of 32 j
    const int jt0 = s * niter;

    const __hip_bfloat16* Kb = Kq + (size_t)b * 8192 * 16;
    const __hip_bfloat16* Vb = Vswz + (size_t)b * 262144 + h * 256 + m * 8;

    // Q B-frag (regs): B[k=8h+idx][n=m] = Kq[i0+m][8h+idx]
    const bf16x8 bq = *(const bf16x8*)(Kb + (size_t)(i0 + m) * 16 + h * 8);

    floatx16 oa = {};
    float l0 = 0.f, l1 = 0.f, l2 = 0.f, l3 = 0.f;

    // ---- software pipeline: preload tile jt0 ----
    bf16x8 ak = *(const bf16x8*)(Kb + (size_t)(jt0 * 32 + m) * 16 + h * 8);
    bf16x8 vb0 = *(const bf16x8*)(Vb + (size_t)jt0 * 1024 + 0);
    bf16x8 vb1 = *(const bf16x8*)(Vb + (size_t)jt0 * 1024 + 512);

#pragma unroll 2
    for (int it = 0; it < niter; ++it) {
        const bf16x8 cak = ak;
        const bf16x8 cv0 = vb0, cv1 = vb1;
        if (it + 1 < niter) {
            const int jn = jt0 + it + 1;
            ak  = *(const bf16x8*)(Kb + (size_t)(jn * 32 + m) * 16 + h * 8);
            vb0 = *(const bf16x8*)(Vb + (size_t)jn * 1024 + 0);
            vb1 = *(const bf16x8*)(Vb + (size_t)jn * 1024 + 512);
        }

        // S^T(32j x 32i) = K(A) x Q(B), K=16 exact
        floatx16 sc = __builtin_amdgcn_mfma_f32_32x32x16_bf16(cak, bq, (floatx16){}, 0, 0, 0);

        // P = 2^S ; sc reg 4g+idx holds j_loc = 8g+4h+idx, i = m.
        // cvt_pk pairs ARE the A-frag dwords under the v7 V-swizzle.
#pragma unroll
        for (int half = 0; half < 2; ++half) {
            u32x4 pau;
#pragma unroll
            for (int gg = 0; gg < 2; ++gg) {
                const int g = half * 2 + gg;
                float e0 = __builtin_amdgcn_exp2f(sc[4 * g + 0]);
                float e1 = __builtin_amdgcn_exp2f(sc[4 * g + 1]);
                float e2 = __builtin_amdgcn_exp2f(sc[4 * g + 2]);
                float e3 = __builtin_amdgcn_exp2f(sc[4 * g + 3]);
                l0 += e0; l1 += e1; l2 += e2; l3 += e3;
#if defined(__has_builtin) && __has_builtin(__builtin_amdgcn_cvt_pk_bf16_f32)
                bf16x2 pk0 = __builtin_amdgcn_cvt_pk_bf16_f32(e0, e1);
                bf16x2 pk1 = __builtin_amdgcn_cvt_pk_bf16_f32(e2, e3);
#else
                bf16x2 pk0 = {(__bf16)e0, (__bf16)e1};
                bf16x2 pk1 = {(__bf16)e2, (__bf16)e3};
#endif
                pau[gg * 2 + 0] = __builtin_bit_cast(unsigned, pk0);
                pau[gg * 2 + 1] = __builtin_bit_cast(unsigned, pk1);
            }
            bf16x8 pa = __builtin_bit_cast(bf16x8, pau);
            oa = __builtin_amdgcn_mfma_f32_32x32x16_bf16(pa, half ? cv1 : cv0, oa, 0, 0, 0);
        }
    }

    // full split-partial row-sum l_s for row i0+m (this lane's column)
    float l = (l0 + l1) + (l2 + l3);
    l += __shfl_xor(l, 32);
    const float rinv = __builtin_amdgcn_rcpf(l);

    // store normalized ratios r_s = O_s / l_s as bf16 (unit-scale, well-conditioned).
    // reg r -> row i_loc=(r&3)+8*(r>>2)+4h, col c=m ; l for row iloc lives in lane iloc
#pragma unroll
    for (int r = 0; r < 16; ++r) {
        int iloc = (r & 3) + 8 * (r >> 2) + 4 * h;
        float lr = __shfl(rinv, iloc);
        size_t row = (size_t)b * 8192 + i0 + iloc;
        Opart[((row << LSPLIT) | s) * 32 + m] = __float2bfloat16(oa[r] * lr);
    }
    if (h == 0)
        Lpart[(((size_t)b * 8192 + i0 + m) << LSPLIT) | s] = l;
}

// ---------------- Kernel C: weighted combine + epilogue ----------------
// out = (sum_s l_s * r_s) / (sum_s l_s) * gamma + in   (8 splits, LSPLIT=3)
// v5 combine (R13): 4 channels/thread, ushort4 Opart loads + float4 in/out.
__global__ __launch_bounds__(256) void combine_kernel(
    const unsigned short* __restrict__ Opart, const float* __restrict__ Lpart,
    const float* __restrict__ in, const float* __restrict__ gamma,
    float* __restrict__ out)
{
    const int gid = blockIdx.x * 256 + threadIdx.x;   // 0..131071
    const int row = gid >> 3;                          // 0..16383
    const int c4 = (gid & 7) * 4;
    const unsigned short* op = Opart + ((size_t)row << LSPLIT) * 32 + c4;
    const float* lp = Lpart + ((size_t)row << LSPLIT);
    float4 lv0 = *(const float4*)(lp);
    float4 lv1 = *(const float4*)(lp + 4);
    float ls8[8] = {lv0.x, lv0.y, lv0.z, lv0.w, lv1.x, lv1.y, lv1.z, lv1.w};
    float a0 = 0.f, a1 = 0.f, a2 = 0.f, a3 = 0.f;
    float lsum = 0.f;
#pragma unroll
    for (int s = 0; s < (1 << LSPLIT); ++s) {
        ushort4 u = *(const ushort4*)(op + s * 32);
        float ls = ls8[s];
        a0 += ls * __uint_as_float((unsigned)u.x << 16);
        a1 += ls * __uint_as_float((unsigned)u.y << 16);
        a2 += ls * __uint_as_float((unsigned)u.z << 16);
        a3 += ls * __uint_as_float((unsigned)u.w << 16);
        lsum += ls;
    }
    const size_t base = (size_t)row * 32 + c4;
    float4 x = *(const float4*)(in + base);
    const float gl = gamma[0] / lsum;
    float4 r;
    r.x = a0 * gl + x.x;
    r.y = a1 * gl + x.y;
    r.z = a2 * gl + x.z;
    r.w = a3 * gl + x.w;
    *(float4*)(out + base) = r;
}

extern "C" void kernel_launch(void* const* d_in, const int* in_sizes, int n_in,
                              void* d_out, int out_size, void* d_ws, size_t ws_size,
                              hipStream_t stream) {
    const float* in = (const float*)d_in[0];
    const float* W1 = (const float*)d_in[1];
    const float* b1 = (const float*)d_in[2];
    const float* W2 = (const float*)d_in[3];
    const float* b2 = (const float*)d_in[4];
    const float* gamma = (const float*)d_in[5];
    float* out = (float*)d_out;

    __hip_bfloat16* Kq = (__hip_bfloat16*)d_ws;
    __hip_bfloat16* Vswz = Kq + KQ_ELEMS;
    __hip_bfloat16* Opart = (__hip_bfloat16*)((char*)d_ws + OPART_OFF);
    float* Lpart = (float*)(Opart + ((size_t)16384 << LSPLIT) * 32);

    proj_kernel<<<1024, 256, 0, stream>>>(in, W1, b1, W2, b2, Kq, Vswz);
    flash_kernel<<<2 * 64 * (1 << LSPLIT), 256, 0, stream>>>(Kq, Vswz, Opart, Lpart);
    combine_kernel<<<512, 256, 0, stream>>>((const unsigned short*)Opart, Lpart, in, gamma, out);
}